// Round 6
// baseline (50.555 us; speedup 1.0000x reference)
//
#include <hip/hip_runtime.h>
#include <hip/hip_bf16.h>

typedef __attribute__((ext_vector_type(8))) short short8;
typedef __attribute__((ext_vector_type(4))) float f32x4;

#define WPB 16
#define BLOCK 1024
#define TPW 2                         // tokens per wave
#define NROW (2 * TPW)                // row stream: Q0,K0,Q1,K1
#define W_PITCH 528                   // 256 bf16 + 16B pad
#define W_MAT (64 * W_PITCH)          // 33792
#define QK_PITCH 144                  // 64 bf16 + 16B pad
#define QK_TILE (16 * QK_PITCH)       // 2304
#define LDS_W (2 * W_MAT)             // 67584
#define SCR_PW (2 * QK_TILE)          // Q tile + K tile per wave
#define LDS_TOTAL (LDS_W + WPB * SCR_PW)  // 141312 -> 16 waves/CU

union S8U { short8 s; unsigned u[4]; };

__device__ __forceinline__ unsigned pk2(float a, float b) {
  __hip_bfloat162 h = __float22bfloat162_rn(make_float2(a, b));
  return *reinterpret_cast<unsigned*>(&h);
}
__device__ __forceinline__ unsigned short bf1(float a) {
  __hip_bfloat16 h = __float2bfloat16(a);
  return *reinterpret_cast<unsigned short*>(&h);
}

// issue 8 global_load_dwordx4 for half H (k-steps 4H..4H+3) of row RP into raw
#define ISSUE(RP, H) {                                                        \
  _Pragma("unroll") for (int j_ = 0; j_ < 4; ++j_) {                          \
    raw[2 * j_]     = *(const float4*)((RP) + (4 * (H) + j_) * 32);           \
    raw[2 * j_ + 1] = *(const float4*)((RP) + (4 * (H) + j_) * 32 + 4);       \
  } }

// convert raw half -> bf16 frags bfb[4H..4H+3] (waits on raw's loads)
#define CONV(H) {                                                             \
  _Pragma("unroll") for (int j_ = 0; j_ < 4; ++j_) {                          \
    S8U u_;                                                                   \
    u_.u[0] = pk2(raw[2 * j_].x, raw[2 * j_].y);                              \
    u_.u[1] = pk2(raw[2 * j_].z, raw[2 * j_].w);                              \
    u_.u[2] = pk2(raw[2 * j_ + 1].x, raw[2 * j_ + 1].y);                      \
    u_.u[3] = pk2(raw[2 * j_ + 1].z, raw[2 * j_ + 1].w);                      \
    bfb[4 * (H) + j_] = u_.s;                                                 \
  } }

// MFMA quarter: k-steps K0..K0+3 against W-LDS WL into ACC
#define MF(K0, WL, ACC) {                                                     \
  _Pragma("unroll") for (int ks_ = (K0); ks_ < (K0) + 4; ++ks_) {             \
    _Pragma("unroll") for (int n_ = 0; n_ < 4; ++n_) {                        \
      short8 b_ = *(const short8*)((WL) + (n_ * 16 + e) * W_PITCH + ks_ * 64 + g * 16); \
      ACC[n_] = __builtin_amdgcn_mfma_f32_16x16x32_bf16(bfb[ks_], b_, ACC[n_], 0, 0, 0); \
    } }  }

// C-frag (row=g*4+r, col=n*16+e) -> row-major bf16 tile
#define WRITET(ACC, TB) {                                                     \
  unsigned short* tw_ = (unsigned short*)(TB);                                \
  _Pragma("unroll") for (int n_ = 0; n_ < 4; ++n_)                            \
    _Pragma("unroll") for (int r_ = 0; r_ < 4; ++r_)                          \
      tw_[(g * 4 + r_) * 72 + n_ * 16 + e] = bf1(ACC[n_][r_]); }

#define SBAR __builtin_amdgcn_sched_barrier(0)

__global__ __launch_bounds__(BLOCK) void attrouter_kernel(
    const float* __restrict__ ig, const float* __restrict__ qev,
    const float* __restrict__ kev, const float* __restrict__ Wq,
    const float* __restrict__ Wk, float* __restrict__ out, int ntok)
{
  extern __shared__ char smem[];
  const int tid  = threadIdx.x;
  const int lane = tid & 63;
  const int wv   = tid >> 6;
  const int e    = lane & 15;
  const int g    = lane >> 4;

  // ---- stage W^T (bf16) into LDS; fold 1/sqrt(64) into Wq (exact 2^-3) ----
  {
    #pragma unroll
    for (int i = 0; i < 2; ++i) {
      int tile = tid + i * BLOCK;            // 0..2047
      int m  = tile >> 10;
      int r  = tile & 1023;
      int d0 = (r >> 4) * 4;
      int a0 = (r & 15) * 4;
      const float* wsrc = m ? Wk : Wq;
      const float scl = m ? 1.0f : 0.125f;
      const float* src = wsrc + d0 * 64 + a0;
      float4 r0 = *(const float4*)(src);
      float4 r1 = *(const float4*)(src + 64);
      float4 r2 = *(const float4*)(src + 128);
      float4 r3 = *(const float4*)(src + 192);
      float c0[4] = {r0.x, r0.y, r0.z, r0.w};
      float c1[4] = {r1.x, r1.y, r1.z, r1.w};
      float c2[4] = {r2.x, r2.y, r2.z, r2.w};
      float c3[4] = {r3.x, r3.y, r3.z, r3.w};
      #pragma unroll
      for (int j = 0; j < 4; ++j) {
        uint2 v;
        v.x = pk2(scl * c0[j], scl * c1[j]);
        v.y = pk2(scl * c2[j], scl * c3[j]);
        *(uint2*)(smem + m * W_MAT + (a0 + j) * W_PITCH + d0 * 2) = v;
      }
    }
  }
  __syncthreads();

  char* qt = smem + LDS_W + wv * SCR_PW;
  char* kt = qt + QK_TILE;
  const int wbase = (blockIdx.x * WPB + wv) * TPW;

  // row pointers: Q0,K0,Q1,K1 (clamped tokens; recomputed output only for valid)
  const float* rp[NROW];
  int tkn[TPW];
  #pragma unroll
  for (int t = 0; t < TPW; ++t) {
    tkn[t] = (wbase + t < ntok) ? (wbase + t) : (ntok - 1);
    rp[2 * t]     = qev + (size_t)tkn[t] * 4096 + e * 256 + g * 8;
    rp[2 * t + 1] = kev + (size_t)tkn[t] * 4096 + e * 256 + g * 8;
  }

  float4 raw[8];
  short8 bfb[8];

  // prologue: half0 of row0 in flight
  ISSUE(rp[0], 0); SBAR;

  #pragma unroll
  for (int r = 0; r < NROW; ++r) {
    const char* wl = smem + (r & 1) * W_MAT;
    f32x4 acc[4] = {{0,0,0,0},{0,0,0,0},{0,0,0,0},{0,0,0,0}};

    CONV(0);                         // waits half0(row r)
    ISSUE(rp[r], 1); SBAR;           // half1 in flight under MF
    MF(0, wl, acc);
    CONV(1);                         // waits half1(row r)
    if (r < NROW - 1) { ISSUE(rp[r + 1], 0); SBAR; }   // unrolled: no branch
    MF(4, wl, acc);
    WRITET(acc, (r & 1) ? kt : qt);

    if (r & 1) {
      // ---- sim^T = mfma(K, Q); softmax over k; gate; final softmax ----
      const int tok = tkn[r >> 1];
      short8 fq0 = *(const short8*)(qt + e * QK_PITCH + g * 16);
      short8 fq1 = *(const short8*)(qt + e * QK_PITCH + 64 + g * 16);
      short8 fk0 = *(const short8*)(kt + e * QK_PITCH + g * 16);
      short8 fk1 = *(const short8*)(kt + e * QK_PITCH + 64 + g * 16);
      f32x4 s = {0,0,0,0};
      s = __builtin_amdgcn_mfma_f32_16x16x32_bf16(fk0, fq0, s, 0, 0, 0);
      s = __builtin_amdgcn_mfma_f32_16x16x32_bf16(fk1, fq1, s, 0, 0, 0);
      float4 igv = *(const float4*)(ig + (size_t)tok * 16 + g * 4);
      float p0 = __expf(s[0]), p1 = __expf(s[1]);
      float p2 = __expf(s[2]), p3 = __expf(s[3]);
      float sg = p0 * igv.x + p1 * igv.y + p2 * igv.z + p3 * igv.w;
      float se = (p0 + p1) + (p2 + p3);
      sg += __shfl_xor(sg, 16); se += __shfl_xor(se, 16);
      sg += __shfl_xor(sg, 32); se += __shfl_xor(se, 32);
      float ev = __expf(sg / se);
      float ss = ev;
      ss += __shfl_xor(ss, 1); ss += __shfl_xor(ss, 2);
      ss += __shfl_xor(ss, 4); ss += __shfl_xor(ss, 8);
      if (g == 0 && wbase + (r >> 1) < ntok)
        out[(size_t)tok * 16 + e] = ev / ss;
    }
  }
}

extern "C" void kernel_launch(void* const* d_in, const int* in_sizes, int n_in,
                              void* d_out, int out_size, void* d_ws, size_t ws_size,
                              hipStream_t stream) {
  const float* ig  = (const float*)d_in[0];
  const float* qev = (const float*)d_in[1];
  const float* kev = (const float*)d_in[2];
  const float* Wq  = (const float*)d_in[3];
  const float* Wk  = (const float*)d_in[4];
  float* out = (float*)d_out;
  int ntok = in_sizes[1] >> 12;    // B*S

  hipFuncSetAttribute((const void*)attrouter_kernel,
                      hipFuncAttributeMaxDynamicSharedMemorySize, LDS_TOTAL);

  int grid = (ntok + WPB * TPW - 1) / (WPB * TPW);   // 256 at ntok=8192
  attrouter_kernel<<<grid, BLOCK, LDS_TOTAL, stream>>>(ig, qev, kev, Wq, Wk, out, ntok);
}